// Round 6
// baseline (16438.403 us; speedup 1.0000x reference)
//
#include <hip/hip_runtime.h>
#include <cstdint>

// ---------------------------------------------------------------------------
// BiLSTM-CRF on MI355X.
// Sizes: V=100000 E=300 H=256 S=4096 L=32 NC=64 CE=25 CO=25 T=12 START=10 STOP=11
// Output: f32[1] = forward_score - gold_score
//
// k_lstm (round 6): K-sliced GEMV, 512 threads/block (8 waves, 2/SIMD), grid=2.
// Thread (w,l): slice=(l>>4) covers h[slice*64..+64); rows r=w*128+(l&15)+16k.
// 256 weight pairs/thread ALL in registers: j<14 VGPR (112), j>=14 AGPR (144).
// Partials -> LDS pbuf[row][slice]; cell threads (tid<256) sum 4 slices + gi,
// do c/h update, write h f16. Zero LDS weight traffic; 2-wave TLP hides DS.
// ---------------------------------------------------------------------------

#define S_LEN 4096
#define EMB_LD 328            // embeds row stride (325 padded to 16B multiple)

typedef _Float16 half2_t __attribute__((ext_vector_type(2)));
typedef unsigned int u32x4 __attribute__((ext_vector_type(4)));

__device__ __forceinline__ float fdot2(unsigned int a, unsigned int b, float acc) {
#if __has_builtin(__builtin_amdgcn_fdot2)
    return __builtin_amdgcn_fdot2(__builtin_bit_cast(half2_t, a),
                                  __builtin_bit_cast(half2_t, b), acc, false);
#else
    half2_t x = __builtin_bit_cast(half2_t, a);
    half2_t y = __builtin_bit_cast(half2_t, b);
    return acc + (float)x[0]*(float)y[0] + (float)x[1]*(float)y[1];
#endif
}

__device__ __forceinline__ unsigned int pack2f16(float a, float b) {
    union { _Float16 h[2]; unsigned int u; } v;
    v.h[0] = (_Float16)a; v.h[1] = (_Float16)b; return v.u;
}

__device__ __forceinline__ float sigm(float x) { return 1.0f / (1.0f + __expf(-x)); }

__device__ __forceinline__ float ftanh(float x) {
    float ax = fabsf(x);
    float e = __expf(-2.0f * ax);          // in (0,1], no overflow
    float t = (1.0f - e) / (1.0f + e);
    return copysignf(t, x);
}

// ---------------------------------------------------------------------------
// Workspace layout (bytes, all 256-aligned)
// ---------------------------------------------------------------------------
static constexpr size_t WS_EMBEDS = 0;                                // f32[4096][328]
static constexpr size_t WS_GI     = WS_EMBEDS + (size_t)4096*328*4;   // f32[2][4096][1024] ([s][cell][gate])
static constexpr size_t WS_WV     = WS_GI     + (size_t)2*4096*1024*4;// u32[2][57344]
static constexpr size_t WS_WA     = WS_WV     + (size_t)2*57344*4;    // u32[2][73728]
static constexpr size_t WS_CFEAT  = WS_WA     + (size_t)2*73728*4;    // f32[4096][25]
static constexpr size_t WS_HS     = WS_CFEAT  + (size_t)4096*25*4;    // f32[2][4096][256]
static constexpr size_t WS_FEATS  = WS_HS     + (size_t)2*4096*256*4; // f32[4096][12]
static constexpr size_t WS_CHUNKS = WS_FEATS  + (size_t)4096*12*4;    // f32[256][144]
static constexpr size_t WS_LVL2   = WS_CHUNKS + (size_t)256*144*4;    // f32[16][144]
static constexpr size_t WS_SCAL   = WS_LVL2   + (size_t)16*144*4;     // f32 scalars

// ---------------------------------------------------------------------------
// K1: pack Whh (fwd+bwd) to f16 for the K-sliced layout.
// Row r: w=r>>7, sub=r&15, k=(r>>4)&7. Pair p: slice=p>>5, j=p&31, lane=slice*16+sub.
// j<14  -> wv[dir][((k*14+j)*8+w)*64+lane]      (VGPR tier)
// j>=14 -> wa[dir][((k*18+j-14)*8+w)*64+lane]   (AGPR tier)
// ---------------------------------------------------------------------------
__global__ void k_pack(const float* __restrict__ whhf, const float* __restrict__ whhb,
                       unsigned int* __restrict__ wv, unsigned int* __restrict__ wa) {
    int idx = blockIdx.x * 256 + threadIdx.x;           // 0..2047
    if (idx >= 2048) return;
    int dir = idx >> 10, r = idx & 1023;
    const float* W = (dir ? whhb : whhf) + r * 256;
    int w = r >> 7, sub = r & 15, k = (r >> 4) & 7;
    unsigned int* wvp = wv + (size_t)dir * 57344;
    unsigned int* wap = wa + (size_t)dir * 73728;
    for (int p = 0; p < 128; p++) {
        unsigned int val = pack2f16(W[2*p], W[2*p + 1]);
        int slice = p >> 5, j = p & 31;
        int lane = slice * 16 + sub;
        if (j < 14) wvp[((k * 14 + j) * 8 + w) * 64 + lane] = val;
        else        wap[((k * 18 + (j - 14)) * 8 + w) * 64 + lane] = val;
    }
}

// ---------------------------------------------------------------------------
// K2: char CNN  (one block per word)
// ---------------------------------------------------------------------------
__global__ void k_charcnn(const int* __restrict__ chars, const float* __restrict__ cemb,
                          const float* __restrict__ convw, const float* __restrict__ convb,
                          float* __restrict__ cfeat) {
    int s = blockIdx.x, tid = threadIdx.x;              // 128 threads
    __shared__ float ce[32][25];
    __shared__ float wz[1875];                          // [25][3][25]
    __shared__ float bias[25];
    __shared__ float conv[850];                         // [34][25]
    for (int i = tid; i < 800; i += 128)
        ce[i / 25][i % 25] = cemb[chars[s * 32 + i / 25] * 25 + (i % 25)];
    for (int i = tid; i < 1875; i += 128) wz[i] = convw[i];
    if (tid < 25) bias[tid] = convb[tid];
    __syncthreads();
    for (int p = tid; p < 850; p += 128) {
        int tt = p / 25, o = p % 25;
        float acc = 0.f;
        #pragma unroll
        for (int kh = 0; kh < 3; kh++) {
            int tr = tt - 2 + kh;
            if (tr >= 0 && tr < 32) {
                const float* wrow = &wz[o * 75 + kh * 25];
                #pragma unroll
                for (int kw = 0; kw < 25; kw++) acc += ce[tr][kw] * wrow[kw];
            }
        }
        conv[p] = acc;
    }
    __syncthreads();
    if (tid < 25) {
        float m = conv[tid];
        for (int tt = 1; tt < 34; tt++) m = fmaxf(m, conv[tt * 25 + tid]);
        cfeat[s * 25 + tid] = m + bias[tid];
    }
}

// ---------------------------------------------------------------------------
// K3: embeds[s] = [ word_embed[sentence[s]] (300) | cfeat[s] (25) ]  stride 328
// ---------------------------------------------------------------------------
__global__ void k_embeds(const int* __restrict__ sentence, const float* __restrict__ wemb,
                         const float* __restrict__ cfeat, float* __restrict__ embeds) {
    int s = blockIdx.x, tid = threadIdx.x;              // 128 threads
    const float4* src = (const float4*)(wemb + (size_t)sentence[s] * 300);
    float4* dst = (float4*)(embeds + (size_t)s * EMB_LD);
    for (int i = tid; i < 75; i += 128) dst[i] = src[i];
    if (tid < 25) embeds[(size_t)s * EMB_LD + 300 + tid] = cfeat[s * 25 + tid];
    if (tid >= 25 && tid < 28) embeds[(size_t)s * EMB_LD + 325 + (tid - 25)] = 0.f; // pad
}

// ---------------------------------------------------------------------------
// K4: GEMM  gi = embeds @ Wih^T + b, output layout [dir][s][cell][gate]
// ---------------------------------------------------------------------------
__global__ __launch_bounds__(256) void k_gemm(const float* __restrict__ A,
        const float* __restrict__ Bf, const float* __restrict__ Bb,
        const float* __restrict__ bf, const float* __restrict__ bb,
        float* __restrict__ gi) {
    int bs = blockIdx.x;            // s-tile  [0,64)
    int br = blockIdx.y;            // row-tile [0,32)
    int dir = br >> 4;
    int row0 = (br & 15) * 64;
    const float* B = dir ? Bb : Bf;
    const float* bias = dir ? bb : bf;
    __shared__ float As[16][65], Bs[16][65];
    int tid = threadIdx.x;
    int tx = tid & 15, ty = tid >> 4;
    int s0 = bs * 64;
    float acc[4][4] = {};
    int lr = tid >> 2, lc0 = (tid & 3) * 4;
    for (int k0 = 0; k0 < 325; k0 += 16) {
        #pragma unroll
        for (int i = 0; i < 4; i++) {
            int k = k0 + lc0 + i;
            As[lc0 + i][lr] = (k < 325) ? A[(size_t)(s0 + lr) * EMB_LD + k] : 0.f;
            Bs[lc0 + i][lr] = (k < 325) ? B[(size_t)(row0 + lr) * 325 + k] : 0.f;
        }
        __syncthreads();
        #pragma unroll
        for (int kk = 0; kk < 16; kk++) {
            float a[4], b[4];
            #pragma unroll
            for (int i = 0; i < 4; i++) a[i] = As[kk][ty * 4 + i];
            #pragma unroll
            for (int j = 0; j < 4; j++) b[j] = Bs[kk][tx * 4 + j];
            #pragma unroll
            for (int i = 0; i < 4; i++)
                #pragma unroll
                for (int j = 0; j < 4; j++) acc[i][j] += a[i] * b[j];
        }
        __syncthreads();
    }
    #pragma unroll
    for (int i = 0; i < 4; i++)
        #pragma unroll
        for (int j = 0; j < 4; j++) {
            int row = row0 + tx * 4 + j;                 // 0..1023 = gate*256+cell
            int s   = s0 + ty * 4 + i;
            gi[(size_t)dir * 4194304 + (size_t)s * 1024 + (row & 255) * 4 + (row >> 8)]
                = acc[i][j] + bias[row];
        }
}

// ---------------------------------------------------------------------------
// K5: recurrence. grid=2 (direction), 512 threads, 2 waves/SIMD.
// ---------------------------------------------------------------------------
__global__ __launch_bounds__(512, 1)
__attribute__((amdgpu_waves_per_eu(2, 2)))
void k_lstm(const unsigned int* __restrict__ wv, const unsigned int* __restrict__ wa,
            const float* __restrict__ gi, float* __restrict__ hs) {
    const int dir = blockIdx.x;
    const int tid = threadIdx.x;                        // 0..511
    const int w = tid >> 6, l = tid & 63;
    const int slice = l >> 4, sub = l & 15;
    __shared__ __align__(16) float pbuf[4096];          // [row 1024][slice 4]
    __shared__ __align__(16) unsigned int hbuf[256];    // 2 buffers x 128 f16-pairs

    // ---- VGPR-tier weights: wvr[k][j], 112 u32 (slice pairs j=0..13) ----
    unsigned int wvr[8][14];
    const unsigned int* wvb = wv + (size_t)dir * 57344;
    #pragma unroll
    for (int k = 0; k < 8; k++)
        #pragma unroll
        for (int j = 0; j < 14; j++)
            wvr[k][j] = wvb[((k * 14 + j) * 8 + w) * 64 + l];

    // ---- AGPR-tier weights: areg[k][j], 144 u32 (slice pairs j=14..31) ----
    unsigned int areg[8][18];
    {
        const unsigned int* wab = wa + (size_t)dir * 73728;
        #pragma unroll
        for (int k = 0; k < 8; k++)
            #pragma unroll
            for (int j = 0; j < 18; j++) {
                unsigned int v = wab[((k * 18 + j) * 8 + w) * 64 + l];
                asm("v_accvgpr_write_b32 %0, %1" : "=a"(areg[k][j]) : "v"(v));
            }
    }

    if (tid < 256) hbuf[tid] = 0u;                      // zero both h buffers
    __syncthreads();

    const float* gib = gi + (size_t)dir * 4194304;
    float* hsb = hs + (size_t)dir * 1048576;
    const bool fw = (dir == 0);
    float c = 0.f;
    float4 gpre = make_float4(0.f, 0.f, 0.f, 0.f);
    if (tid < 256) {
        int sq0 = fw ? 0 : (S_LEN - 1);
        gpre = *(const float4*)(gib + (size_t)sq0 * 1024 + tid * 4);
    }
    const int pwbase = (w * 128 + sub) * 4 + slice;     // pbuf word for k=0

    #pragma clang loop unroll(disable)
    for (int s = 0; s < S_LEN; s++) {
        // ---- phase 1: 8 row-partials over my 64-elem h slice ----
        const u32x4* hq = (const u32x4*)(hbuf + (s & 1) * 128);
        u32x4 h4[8];
        #pragma unroll
        for (int i = 0; i < 8; i++) h4[i] = hq[slice * 8 + i];

        #pragma unroll
        for (int k = 0; k < 8; k++) {
            float a = 0.f;
            #pragma unroll
            for (int j = 0; j < 14; j++)
                a = fdot2(wvr[k][j], h4[j >> 2][j & 3], a);
            #pragma unroll
            for (int j = 14; j < 32; j++) {
                unsigned int wt;
                asm("v_accvgpr_read_b32 %0, %1" : "=v"(wt) : "a"(areg[k][j - 14]));
                a = fdot2(wt, h4[j >> 2][j & 3], a);
            }
            pbuf[pwbase + 64 * k] = a;                  // [row][slice], conflict-free
        }
        __syncthreads();                                // B1: partials visible

        // ---- phase 2: cell update (threads 0..255 = waves 0..3) ----
        if (tid < 256) {
            const float4* pb4 = (const float4*)pbuf;
            float4 pi = pb4[tid];
            float4 pf = pb4[256 + tid];
            float4 pg = pb4[512 + tid];
            float4 po = pb4[768 + tid];
            float si = sigm (((pi.x + pi.y) + (pi.z + pi.w)) + gpre.x);
            float sf = sigm (((pf.x + pf.y) + (pf.z + pf.w)) + gpre.y);
            float tg = ftanh(((pg.x + pg.y) + (pg.z + pg.w)) + gpre.z);
            float so = sigm (((po.x + po.y) + (po.z + po.w)) + gpre.w);
            c = sf * c + si * tg;
            float h = so * ftanh(c);
            int sq = fw ? s : (S_LEN - 1 - s);
            hsb[(size_t)sq * 256 + tid] = h;
            union { _Float16 hh; unsigned short u; } cv; cv.hh = (_Float16)h;
            ((unsigned short*)(hbuf + ((s + 1) & 1) * 128))[tid] = cv.u;
            int sn  = (s < S_LEN - 1) ? s + 1 : s;      // prefetch next gi
            int sqn = fw ? sn : (S_LEN - 1 - sn);
            gpre = *(const float4*)(gib + (size_t)sqn * 1024 + tid * 4);
        }
        __syncthreads();                                // B2: next h published
    }
}

// ---------------------------------------------------------------------------
// K6: feats[s][j] = b_tag[j] + hs_f[s]·W_tag[j][0:256] + hs_b[s]·W_tag[j][256:512]
// ---------------------------------------------------------------------------
__global__ void k_feats(const float* __restrict__ hs, const float* __restrict__ wtag,
                        const float* __restrict__ btag, float* __restrict__ feats) {
    int s = blockIdx.x, tid = threadIdx.x;               // 192 threads
    int j = tid >> 4, l = tid & 15;
    const float* hf = hs + (size_t)s * 256;
    const float* hb = hs + 1048576 + (size_t)s * 256;
    const float* w = wtag + j * 512;
    float p = 0.f;
    int k0 = l * 16;
    #pragma unroll
    for (int k = 0; k < 16; k++) p += hf[k0 + k] * w[k0 + k];
    #pragma unroll
    for (int k = 0; k < 16; k++) p += hb[k0 + k] * w[256 + k0 + k];
    p += __shfl_down(p, 8, 16);
    p += __shfl_down(p, 4, 16);
    p += __shfl_down(p, 2, 16);
    p += __shfl_down(p, 1, 16);
    if (l == 0) feats[s * 12 + j] = btag[j] + p;
}

// ---------------------------------------------------------------------------
// K7: gold score (single block)
// ---------------------------------------------------------------------------
__global__ void k_gold(const float* __restrict__ feats, const int* __restrict__ tags,
                       const float* __restrict__ trans, float* __restrict__ scal) {
    __shared__ float red[256];
    int tid = threadIdx.x;
    float p = 0.f;
    for (int s = tid; s < S_LEN; s += 256) {
        int tg = tags[s];
        p += feats[s * 12 + tg];
        int prev = (s == 0) ? 10 : tags[s - 1];
        p += trans[prev * 12 + tg];
    }
    if (tid == 0) p += trans[tags[S_LEN - 1] * 12 + 11];
    red[tid] = p;
    __syncthreads();
    for (int off = 128; off; off >>= 1) {
        if (tid < off) red[tid] += red[tid + off];
        __syncthreads();
    }
    if (tid == 0) scal[0] = red[0];
}

// ---------------------------------------------------------------------------
// CRF as ordered log-matmul tree-reduction.  M_s[i][j] = trans[i][j] + feat[s][j].
// ---------------------------------------------------------------------------
__device__ __forceinline__ void lse_merge(const float* A, const float* B, float* C, int tid) {
    if (tid < 144) {
        int i = tid / 12, j = tid % 12;
        float m = -1e30f;
        #pragma unroll
        for (int k = 0; k < 12; k++) m = fmaxf(m, A[i * 12 + k] + B[k * 12 + j]);
        float sum = 0.f;
        #pragma unroll
        for (int k = 0; k < 12; k++) sum += __expf(A[i * 12 + k] + B[k * 12 + j] - m);
        C[tid] = m + __logf(sum);
    }
}

// K8: chunk products of 16 consecutive M_s (256 blocks)
__global__ void k_crf1(const float* __restrict__ feats, const float* __restrict__ trans,
                       float* __restrict__ chunks) {
    int b = blockIdx.x, tid = threadIdx.x;               // 192 threads, 144 active
    __shared__ float A[144], Bv[144], Tr[144];
    if (tid < 144) Tr[tid] = trans[tid];
    int s0 = b * 16;
    if (tid < 144) A[tid] = trans[tid] + feats[s0 * 12 + (tid % 12)];
    __syncthreads();
    float* cur = A; float* nxt = Bv;
    for (int s = s0 + 1; s < s0 + 16; s++) {
        if (tid < 144) {
            int i = tid / 12, j = tid % 12;
            float m = -1e30f;
            #pragma unroll
            for (int k = 0; k < 12; k++) m = fmaxf(m, cur[i * 12 + k] + Tr[k * 12 + j]);
            float sum = 0.f;
            #pragma unroll
            for (int k = 0; k < 12; k++) sum += __expf(cur[i * 12 + k] + Tr[k * 12 + j] - m);
            nxt[tid] = feats[s * 12 + j] + m + __logf(sum);
        }
        __syncthreads();
        float* tmp = cur; cur = nxt; nxt = tmp;
    }
    if (tid < 144) chunks[b * 144 + tid] = cur[tid];
}

// K9: fold 16 chunks each (16 blocks)
__global__ void k_crf2(const float* __restrict__ chunks, float* __restrict__ lvl2) {
    int b = blockIdx.x, tid = threadIdx.x;               // 192 threads
    __shared__ float A[144], Bv[144], Cc[144];
    if (tid < 144) A[tid] = chunks[(size_t)(b * 16) * 144 + tid];
    __syncthreads();
    for (int m2 = 1; m2 < 16; m2++) {
        if (tid < 144) Bv[tid] = chunks[(size_t)(b * 16 + m2) * 144 + tid];
        __syncthreads();
        lse_merge(A, Bv, Cc, tid);
        __syncthreads();
        if (tid < 144) A[tid] = Cc[tid];
        __syncthreads();
    }
    if (tid < 144) lvl2[b * 144 + tid] = A[tid];
}

// K10: final fold + score (1 block)
__global__ void k_crf3(const float* __restrict__ lvl2, const float* __restrict__ trans,
                       const float* __restrict__ scal, float* __restrict__ out) {
    __shared__ float A[144], Bv[144], Cc[144], alpha[12];
    int tid = threadIdx.x;                               // 192 threads
    if (tid < 144) A[tid] = lvl2[tid];
    __syncthreads();
    for (int m2 = 1; m2 < 16; m2++) {
        if (tid < 144) Bv[tid] = lvl2[m2 * 144 + tid];
        __syncthreads();
        lse_merge(A, Bv, Cc, tid);
        __syncthreads();
        if (tid < 144) A[tid] = Cc[tid];
        __syncthreads();
    }
    if (tid < 12) {
        int j = tid;
        float m = -1e30f;
        #pragma unroll
        for (int i = 0; i < 12; i++) {
            float v = ((i == 10) ? 0.f : -10000.f) + A[i * 12 + j];
            m = fmaxf(m, v);
        }
        float sum = 0.f;
        #pragma unroll
        for (int i = 0; i < 12; i++) {
            float v = ((i == 10) ? 0.f : -10000.f) + A[i * 12 + j];
            sum += __expf(v - m);
        }
        alpha[j] = m + __logf(sum) + trans[j * 12 + 11];
    }
    __syncthreads();
    if (tid == 0) {
        float m = -1e30f;
        #pragma unroll
        for (int j = 0; j < 12; j++) m = fmaxf(m, alpha[j]);
        float sum = 0.f;
        #pragma unroll
        for (int j = 0; j < 12; j++) sum += __expf(alpha[j] - m);
        out[0] = (m + __logf(sum)) - scal[0];
    }
}

// ---------------------------------------------------------------------------
extern "C" void kernel_launch(void* const* d_in, const int* in_sizes, int n_in,
                              void* d_out, int out_size, void* d_ws, size_t ws_size,
                              hipStream_t stream) {
    const int*   sentence = (const int*)d_in[0];
    const int*   chars    = (const int*)d_in[1];
    const int*   tags     = (const int*)d_in[2];
    const float* wemb     = (const float*)d_in[4];
    const float* cemb     = (const float*)d_in[5];
    const float* convw    = (const float*)d_in[6];
    const float* convb    = (const float*)d_in[7];
    const float* wihf     = (const float*)d_in[8];
    const float* whhf     = (const float*)d_in[9];
    const float* bf       = (const float*)d_in[10];
    const float* wihb     = (const float*)d_in[11];
    const float* whhb     = (const float*)d_in[12];
    const float* bb       = (const float*)d_in[13];
    const float* wtag     = (const float*)d_in[14];
    const float* btag     = (const float*)d_in[15];
    const float* trans    = (const float*)d_in[16];

    char* ws = (char*)d_ws;
    float*        embeds = (float*)(ws + WS_EMBEDS);
    float*        gi     = (float*)(ws + WS_GI);
    unsigned int* wv     = (unsigned int*)(ws + WS_WV);
    unsigned int* wa     = (unsigned int*)(ws + WS_WA);
    float*        cfeat  = (float*)(ws + WS_CFEAT);
    float*        hsbuf  = (float*)(ws + WS_HS);
    float*        feats  = (float*)(ws + WS_FEATS);
    float*        chunks = (float*)(ws + WS_CHUNKS);
    float*        lvl2   = (float*)(ws + WS_LVL2);
    float*        scal   = (float*)(ws + WS_SCAL);

    k_pack<<<8, 256, 0, stream>>>(whhf, whhb, wv, wa);
    k_charcnn<<<4096, 128, 0, stream>>>(chars, cemb, convw, convb, cfeat);
    k_embeds<<<4096, 128, 0, stream>>>(sentence, wemb, cfeat, embeds);
    k_gemm<<<dim3(64, 32), 256, 0, stream>>>(embeds, wihf, wihb, bf, bb, gi);
    k_lstm<<<2, 512, 0, stream>>>(wv, wa, gi, hsbuf);
    k_feats<<<4096, 192, 0, stream>>>(hsbuf, wtag, btag, feats);
    k_gold<<<1, 256, 0, stream>>>(feats, tags, trans, scal);
    k_crf1<<<256, 192, 0, stream>>>(feats, trans, chunks);
    k_crf2<<<16, 192, 0, stream>>>(chunks, lvl2);
    k_crf3<<<1, 192, 0, stream>>>(lvl2, trans, scal, (float*)d_out);
}

// Round 7
// 11232.133 us; speedup vs baseline: 1.4635x; 1.4635x over previous
//
#include <hip/hip_runtime.h>
#include <cstdint>

// ---------------------------------------------------------------------------
// BiLSTM-CRF on MI355X.
// Sizes: V=100000 E=300 H=256 S=4096 L=32 NC=64 CE=25 CO=25 T=12 START=10 STOP=11
// Output: f32[1] = forward_score - gold_score
//
// k_lstm (round 7): 2 CUs PER DIRECTION (grid=4), 512 threads, 2 waves/SIMD.
// Why: f16 Whh per direction = 512 KB = exactly one CU's ENTIRE unified
// V+A register file (per-SIMD pool = 512 regs, m69) -> 1-CU designs must
// stream >=15% of weights from LDS each step (R3-R5 floor ~4700 cy/step).
// Split by CELLS: CU (d,c) owns cells [c*128, c*128+128) -- all 4 gate rows.
//   - weights: 512 rows x 256 K = 128 u32/thread, all VGPR (~175 demand <= 256 cap).
//   - cell update fully local (c-state in-thread, no gate exchange).
//   - cross-CU traffic: h half = 256 B/step via L2 + step-numbered flags
//     (release/acquire agent atomics; 0xAA poison is negative -> safe init;
//     parity double-buffer; backpressure via the flag chain).
//   - matvec two-phase (own half, then partner half) to overlap L2 latency.
// NOTE: requires the 4 WGs co-resident (4 WGs on 256 CUs; CP round-robins SEs).
// ---------------------------------------------------------------------------

#define S_LEN 4096
#define EMB_LD 328            // embeds row stride (325 padded to 16B multiple)
#define GI_BATCH 16

typedef _Float16 half2_t __attribute__((ext_vector_type(2)));

__device__ __forceinline__ float fdot2(unsigned int a, unsigned int b, float acc) {
#if __has_builtin(__builtin_amdgcn_fdot2)
    return __builtin_amdgcn_fdot2(__builtin_bit_cast(half2_t, a),
                                  __builtin_bit_cast(half2_t, b), acc, false);
#else
    half2_t x = __builtin_bit_cast(half2_t, a);
    half2_t y = __builtin_bit_cast(half2_t, b);
    return acc + (float)x[0]*(float)y[0] + (float)x[1]*(float)y[1];
#endif
}

__device__ __forceinline__ unsigned int pack2f16(float a, float b) {
    union { _Float16 h[2]; unsigned int u; } v;
    v.h[0] = (_Float16)a; v.h[1] = (_Float16)b; return v.u;
}

__device__ __forceinline__ float sigm(float x) { return 1.0f / (1.0f + __expf(-x)); }

__device__ __forceinline__ float ftanh(float x) {
    float ax = fabsf(x);
    float e = __expf(-2.0f * ax);          // in (0,1], no overflow
    float t = (1.0f - e) / (1.0f + e);
    return copysignf(t, x);
}

// ---------------------------------------------------------------------------
// Workspace layout (bytes, all 256-aligned)
// ---------------------------------------------------------------------------
static constexpr size_t WS_EMBEDS = 0;                                // f32[4096][328]
static constexpr size_t WS_GI     = WS_EMBEDS + (size_t)4096*328*4;   // f32[2][4096][2][512]
static constexpr size_t WS_WPK    = WS_GI     + (size_t)2*4096*1024*4;// u32[4][128][512]
static constexpr size_t WS_XH     = WS_WPK    + (size_t)4*128*512*4;  // u32[4][2][64]
static constexpr size_t WS_FLAGS  = WS_XH     + 4*2*64*4;             // int[4][16]
static constexpr size_t WS_CFEAT  = WS_FLAGS  + 4*16*4;               // f32[4096][25]
static constexpr size_t WS_HS     = WS_CFEAT  + (size_t)4096*25*4;    // f32[2][4096][256]
static constexpr size_t WS_FEATS  = WS_HS     + (size_t)2*4096*256*4; // f32[4096][12]
static constexpr size_t WS_CHUNKS = WS_FEATS  + (size_t)4096*12*4;    // f32[256][144]
static constexpr size_t WS_LVL2   = WS_CHUNKS + (size_t)256*144*4;    // f32[16][144]
static constexpr size_t WS_SCAL   = WS_LVL2   + (size_t)16*144*4;     // f32 scalars

// ---------------------------------------------------------------------------
// K1: pack Whh (fwd+bwd) to f16 for the 2-CU cell split.
// Row r (= gate*256+cell): cu = d*2 + (cell>>7), thread tid = gate*128 + (cell&127).
// Pair p (h elems 2p,2p+1): own-half pairs first (j = p&63 if (p>>6)==c),
// partner-half pairs second (j = 64 + (p&63)).
// ---------------------------------------------------------------------------
__global__ void k_pack(const float* __restrict__ whhf, const float* __restrict__ whhb,
                       unsigned int* __restrict__ wpk) {
    int idx = blockIdx.x * 256 + threadIdx.x;           // 0..2047 = dir*1024+row
    if (idx >= 2048) return;
    int d = idx >> 10, r = idx & 1023;
    const float* W = (d ? whhb : whhf) + r * 256;
    int gate = r >> 8, cell = r & 255;
    int c = cell >> 7, cl = cell & 127;
    int tid = gate * 128 + cl;
    unsigned int* wb = wpk + (size_t)(d * 2 + c) * 128 * 512;
    for (int p = 0; p < 128; p++) {
        int hp = p >> 6;
        int j = (hp == c) ? (p & 63) : 64 + (p & 63);
        wb[j * 512 + tid] = pack2f16(W[2*p], W[2*p+1]);
    }
}

// ---------------------------------------------------------------------------
// K2: char CNN  (one block per word)
// ---------------------------------------------------------------------------
__global__ void k_charcnn(const int* __restrict__ chars, const float* __restrict__ cemb,
                          const float* __restrict__ convw, const float* __restrict__ convb,
                          float* __restrict__ cfeat) {
    int s = blockIdx.x, tid = threadIdx.x;              // 128 threads
    __shared__ float ce[32][25];
    __shared__ float wz[1875];                          // [25][3][25]
    __shared__ float bias[25];
    __shared__ float conv[850];                         // [34][25]
    for (int i = tid; i < 800; i += 128)
        ce[i / 25][i % 25] = cemb[chars[s * 32 + i / 25] * 25 + (i % 25)];
    for (int i = tid; i < 1875; i += 128) wz[i] = convw[i];
    if (tid < 25) bias[tid] = convb[tid];
    __syncthreads();
    for (int p = tid; p < 850; p += 128) {
        int tt = p / 25, o = p % 25;
        float acc = 0.f;
        #pragma unroll
        for (int kh = 0; kh < 3; kh++) {
            int tr = tt - 2 + kh;
            if (tr >= 0 && tr < 32) {
                const float* wrow = &wz[o * 75 + kh * 25];
                #pragma unroll
                for (int kw = 0; kw < 25; kw++) acc += ce[tr][kw] * wrow[kw];
            }
        }
        conv[p] = acc;
    }
    __syncthreads();
    if (tid < 25) {
        float m = conv[tid];
        for (int tt = 1; tt < 34; tt++) m = fmaxf(m, conv[tt * 25 + tid]);
        cfeat[s * 25 + tid] = m + bias[tid];
    }
}

// ---------------------------------------------------------------------------
// K3: embeds[s] = [ word_embed[sentence[s]] (300) | cfeat[s] (25) ]  stride 328
// ---------------------------------------------------------------------------
__global__ void k_embeds(const int* __restrict__ sentence, const float* __restrict__ wemb,
                         const float* __restrict__ cfeat, float* __restrict__ embeds) {
    int s = blockIdx.x, tid = threadIdx.x;              // 128 threads
    const float4* src = (const float4*)(wemb + (size_t)sentence[s] * 300);
    float4* dst = (float4*)(embeds + (size_t)s * EMB_LD);
    for (int i = tid; i < 75; i += 128) dst[i] = src[i];
    if (tid < 25) embeds[(size_t)s * EMB_LD + 300 + tid] = cfeat[s * 25 + tid];
    if (tid >= 25 && tid < 28) embeds[(size_t)s * EMB_LD + 325 + (tid - 25)] = 0.f; // pad
}

// ---------------------------------------------------------------------------
// K4: GEMM  gi = embeds @ Wih^T + b, output layout [dir][s][c][tidx]
// where c = cell>>7, tidx = gate*128 + (cell&127)  (k_lstm-coalesced).
// ---------------------------------------------------------------------------
__global__ __launch_bounds__(256) void k_gemm(const float* __restrict__ A,
        const float* __restrict__ Bf, const float* __restrict__ Bb,
        const float* __restrict__ bf, const float* __restrict__ bb,
        float* __restrict__ gi) {
    int bs = blockIdx.x;            // s-tile  [0,64)
    int br = blockIdx.y;            // row-tile [0,32)
    int dir = br >> 4;
    int row0 = (br & 15) * 64;
    const float* B = dir ? Bb : Bf;
    const float* bias = dir ? bb : bf;
    __shared__ float As[16][65], Bs[16][65];
    int tid = threadIdx.x;
    int tx = tid & 15, ty = tid >> 4;
    int s0 = bs * 64;
    float acc[4][4] = {};
    int lr = tid >> 2, lc0 = (tid & 3) * 4;
    for (int k0 = 0; k0 < 325; k0 += 16) {
        #pragma unroll
        for (int i = 0; i < 4; i++) {
            int k = k0 + lc0 + i;
            As[lc0 + i][lr] = (k < 325) ? A[(size_t)(s0 + lr) * EMB_LD + k] : 0.f;
            Bs[lc0 + i][lr] = (k < 325) ? B[(size_t)(row0 + lr) * 325 + k] : 0.f;
        }
        __syncthreads();
        #pragma unroll
        for (int kk = 0; kk < 16; kk++) {
            float a[4], b[4];
            #pragma unroll
            for (int i = 0; i < 4; i++) a[i] = As[kk][ty * 4 + i];
            #pragma unroll
            for (int j = 0; j < 4; j++) b[j] = Bs[kk][tx * 4 + j];
            #pragma unroll
            for (int i = 0; i < 4; i++)
                #pragma unroll
                for (int j = 0; j < 4; j++) acc[i][j] += a[i] * b[j];
        }
        __syncthreads();
    }
    #pragma unroll
    for (int i = 0; i < 4; i++)
        #pragma unroll
        for (int j = 0; j < 4; j++) {
            int row = row0 + tx * 4 + j;                 // gate*256+cell
            int s   = s0 + ty * 4 + i;
            int gate = row >> 8, cell = row & 255;
            int cc = cell >> 7, tidx = gate * 128 + (cell & 127);
            gi[(size_t)dir * 4194304 + (size_t)s * 1024 + cc * 512 + tidx]
                = acc[i][j] + bias[row];
        }
}

// ---------------------------------------------------------------------------
// K5: recurrence. grid=4 (dir x cell-half), 512 threads, 2 waves/SIMD.
// ---------------------------------------------------------------------------
__global__ __launch_bounds__(512, 2)
__attribute__((amdgpu_waves_per_eu(2, 2)))
void k_lstm(const unsigned int* __restrict__ wpk, const float* __restrict__ gi,
            unsigned int* __restrict__ xh, int* __restrict__ flags,
            float* __restrict__ hs) {
    const int cu = blockIdx.x;                          // 0..3
    const int d = cu >> 1, c = cu & 1;
    const int tid = threadIdx.x;                        // row-local: gate*128+cl
    __shared__ unsigned int hown[64];                   // own h half (f16 pairs)
    __shared__ unsigned int hpar[64];                   // partner h half
    __shared__ float pre[512];                          // gate preacts

    // 128 weight pairs per thread, all VGPR (fits: ~175 live <= 256/wave @2w/EU)
    unsigned int wreg[128];
    {
        const unsigned int* wb = wpk + (size_t)cu * 128 * 512;
        #pragma unroll
        for (int j = 0; j < 128; j++) wreg[j] = wb[j * 512 + tid];
    }
    if (tid < 64) { hown[tid] = 0u; hpar[tid] = 0u; }
    __syncthreads();

    const float* gib = gi + (size_t)d * 4194304 + c * 512;
    float* hsb = hs + (size_t)d * 1048576 + c * 128;
    unsigned int* xown = xh + cu * 128;                 // [parity][64]
    unsigned int* xpar = xh + (cu ^ 1) * 128;
    int* flago = flags + cu * 16;
    int* flagp = flags + (cu ^ 1) * 16;
    const bool fw = (d == 0);
    float cst = 0.f;
    float g16[GI_BATCH];
    float h8[8];

    for (int s = 0; s < S_LEN; s++) {
        // gi register-batch refill (barriers drain vmcnt; per-step prefetch
        // cannot survive a barrier, so batch 16 steps at once)
        if ((s & (GI_BATCH - 1)) == 0) {
            #pragma unroll
            for (int i = 0; i < GI_BATCH; i++) {
                int ss = s + i;
                int sq = fw ? ss : (S_LEN - 1 - ss);
                g16[i] = gib[(size_t)sq * 1024 + tid];
            }
        }
        float acc = g16[s & (GI_BATCH - 1)];

        // exchange-in: partner h(s) was published at flag value s
        if (s > 0) {
            if (tid == 0)
                while (__hip_atomic_load(flagp, __ATOMIC_ACQUIRE,
                                         __HIP_MEMORY_SCOPE_AGENT) < s) {}
            __syncthreads();                            // B1
            if (tid < 64)
                hpar[tid] = __hip_atomic_load(&xpar[(s & 1) * 64 + tid],
                                              __ATOMIC_RELAXED,
                                              __HIP_MEMORY_SCOPE_AGENT);
        }
        // phase 1: own-half matvec (overlaps hpar loads in flight)
        {
            const uint4* hq = (const uint4*)hown;
            #pragma unroll
            for (int m = 0; m < 16; m++) {
                uint4 h4 = hq[m];
                acc = fdot2(wreg[4*m+0], h4.x, acc);
                acc = fdot2(wreg[4*m+1], h4.y, acc);
                acc = fdot2(wreg[4*m+2], h4.z, acc);
                acc = fdot2(wreg[4*m+3], h4.w, acc);
            }
        }
        __syncthreads();                                // B2: hpar visible
        // phase 3: partner-half matvec
        {
            const uint4* hq = (const uint4*)hpar;
            #pragma unroll
            for (int m = 0; m < 16; m++) {
                uint4 h4 = hq[m];
                acc = fdot2(wreg[64+4*m+0], h4.x, acc);
                acc = fdot2(wreg[64+4*m+1], h4.y, acc);
                acc = fdot2(wreg[64+4*m+2], h4.z, acc);
                acc = fdot2(wreg[64+4*m+3], h4.w, acc);
            }
        }
        pre[tid] = acc;
        __syncthreads();                                // B3: preacts visible
        // phase 4: cell update (tid<128 = own cells)
        if (tid < 128) {
            float pi = pre[tid], pf = pre[128 + tid];
            float pg = pre[256 + tid], po = pre[384 + tid];
            float si = sigm(pi), sf = sigm(pf);
            float tg = ftanh(pg), so = sigm(po);
            cst = sf * cst + si * tg;
            float h = so * ftanh(cst);
            h8[s & 7] = h;                              // write-combine hs
            union { _Float16 hh; unsigned short u; } cv; cv.hh = (_Float16)h;
            ((unsigned short*)hown)[tid] = cv.u;
            if ((s & 7) == 7) {
                #pragma unroll
                for (int i = 0; i < 8; i++) {
                    int ss = s - 7 + i;
                    int sq = fw ? ss : (S_LEN - 1 - ss);
                    hsb[(size_t)sq * 256 + tid] = h8[i];
                }
            }
        }
        __syncthreads();                                // B4: hown = h(s+1)
        // publish h(s+1): wave 0 stores + fences + sets flag = s+1
        if (tid < 64)
            xown[((s + 1) & 1) * 64 + tid] = hown[tid];
        if (tid == 0) {
            __threadfence();
            __hip_atomic_store(flago, s + 1, __ATOMIC_RELEASE,
                               __HIP_MEMORY_SCOPE_AGENT);
        }
    }
}

// ---------------------------------------------------------------------------
// K6: feats[s][j] = b_tag[j] + hs_f[s]·W_tag[j][0:256] + hs_b[s]·W_tag[j][256:512]
// ---------------------------------------------------------------------------
__global__ void k_feats(const float* __restrict__ hs, const float* __restrict__ wtag,
                        const float* __restrict__ btag, float* __restrict__ feats) {
    int s = blockIdx.x, tid = threadIdx.x;               // 192 threads
    int j = tid >> 4, l = tid & 15;
    const float* hf = hs + (size_t)s * 256;
    const float* hb = hs + 1048576 + (size_t)s * 256;
    const float* w = wtag + j * 512;
    float p = 0.f;
    int k0 = l * 16;
    #pragma unroll
    for (int k = 0; k < 16; k++) p += hf[k0 + k] * w[k0 + k];
    #pragma unroll
    for (int k = 0; k < 16; k++) p += hb[k0 + k] * w[256 + k0 + k];
    p += __shfl_down(p, 8, 16);
    p += __shfl_down(p, 4, 16);
    p += __shfl_down(p, 2, 16);
    p += __shfl_down(p, 1, 16);
    if (l == 0) feats[s * 12 + j] = btag[j] + p;
}

// ---------------------------------------------------------------------------
// K7: gold score (single block)
// ---------------------------------------------------------------------------
__global__ void k_gold(const float* __restrict__ feats, const int* __restrict__ tags,
                       const float* __restrict__ trans, float* __restrict__ scal) {
    __shared__ float red[256];
    int tid = threadIdx.x;
    float p = 0.f;
    for (int s = tid; s < S_LEN; s += 256) {
        int tg = tags[s];
        p += feats[s * 12 + tg];
        int prev = (s == 0) ? 10 : tags[s - 1];
        p += trans[prev * 12 + tg];
    }
    if (tid == 0) p += trans[tags[S_LEN - 1] * 12 + 11];
    red[tid] = p;
    __syncthreads();
    for (int off = 128; off; off >>= 1) {
        if (tid < off) red[tid] += red[tid + off];
        __syncthreads();
    }
    if (tid == 0) scal[0] = red[0];
}

// ---------------------------------------------------------------------------
// CRF as ordered log-matmul tree-reduction.  M_s[i][j] = trans[i][j] + feat[s][j].
// ---------------------------------------------------------------------------
__device__ __forceinline__ void lse_merge(const float* A, const float* B, float* C, int tid) {
    if (tid < 144) {
        int i = tid / 12, j = tid % 12;
        float m = -1e30f;
        #pragma unroll
        for (int k = 0; k < 12; k++) m = fmaxf(m, A[i * 12 + k] + B[k * 12 + j]);
        float sum = 0.f;
        #pragma unroll
        for (int k = 0; k < 12; k++) sum += __expf(A[i * 12 + k] + B[k * 12 + j] - m);
        C[tid] = m + __logf(sum);
    }
}

// K8: chunk products of 16 consecutive M_s (256 blocks)
__global__ void k_crf1(const float* __restrict__ feats, const float* __restrict__ trans,
                       float* __restrict__ chunks) {
    int b = blockIdx.x, tid = threadIdx.x;               // 192 threads, 144 active
    __shared__ float A[144], Bv[144], Tr[144];
    if (tid < 144) Tr[tid] = trans[tid];
    int s0 = b * 16;
    if (tid < 144) A[tid] = trans[tid] + feats[s0 * 12 + (tid % 12)];
    __syncthreads();
    float* cur = A; float* nxt = Bv;
    for (int s = s0 + 1; s < s0 + 16; s++) {
        if (tid < 144) {
            int i = tid / 12, j = tid % 12;
            float m = -1e30f;
            #pragma unroll
            for (int k = 0; k < 12; k++) m = fmaxf(m, cur[i * 12 + k] + Tr[k * 12 + j]);
            float sum = 0.f;
            #pragma unroll
            for (int k = 0; k < 12; k++) sum += __expf(cur[i * 12 + k] + Tr[k * 12 + j] - m);
            nxt[tid] = feats[s * 12 + j] + m + __logf(sum);
        }
        __syncthreads();
        float* tmp = cur; cur = nxt; nxt = tmp;
    }
    if (tid < 144) chunks[b * 144 + tid] = cur[tid];
}

// K9: fold 16 chunks each (16 blocks)
__global__ void k_crf2(const float* __restrict__ chunks, float* __restrict__ lvl2) {
    int b = blockIdx.x, tid = threadIdx.x;               // 192 threads
    __shared__ float A[144], Bv[144], Cc[144];
    if (tid < 144) A[tid] = chunks[(size_t)(b * 16) * 144 + tid];
    __syncthreads();
    for (int m2 = 1; m2 < 16; m2++) {
        if (tid < 144) Bv[tid] = chunks[(size_t)(b * 16 + m2) * 144 + tid];
        __syncthreads();
        lse_merge(A, Bv, Cc, tid);
        __syncthreads();
        if (tid < 144) A[tid] = Cc[tid];
        __syncthreads();
    }
    if (tid < 144) lvl2[b * 144 + tid] = A[tid];
}

// K10: final fold + score (1 block)
__global__ void k_crf3(const float* __restrict__ lvl2, const float* __restrict__ trans,
                       const float* __restrict__ scal, float* __restrict__ out) {
    __shared__ float A[144], Bv[144], Cc[144], alpha[12];
    int tid = threadIdx.x;                               // 192 threads
    if (tid < 144) A[tid] = lvl2[tid];
    __syncthreads();
    for (int m2 = 1; m2 < 16; m2++) {
        if (tid < 144) Bv[tid] = lvl2[m2 * 144 + tid];
        __syncthreads();
        lse_merge(A, Bv, Cc, tid);
        __syncthreads();
        if (tid < 144) A[tid] = Cc[tid];
        __syncthreads();
    }
    if (tid < 12) {
        int j = tid;
        float m = -1e30f;
        #pragma unroll
        for (int i = 0; i < 12; i++) {
            float v = ((i == 10) ? 0.f : -10000.f) + A[i * 12 + j];
            m = fmaxf(m, v);
        }
        float sum = 0.f;
        #pragma unroll
        for (int i = 0; i < 12; i++) {
            float v = ((i == 10) ? 0.f : -10000.f) + A[i * 12 + j];
            sum += __expf(v - m);
        }
        alpha[j] = m + __logf(sum) + trans[j * 12 + 11];
    }
    __syncthreads();
    if (tid == 0) {
        float m = -1e30f;
        #pragma unroll
        for (int j = 0; j < 12; j++) m = fmaxf(m, alpha[j]);
        float sum = 0.f;
        #pragma unroll
        for (int j = 0; j < 12; j++) sum += __expf(alpha[j] - m);
        out[0] = (m + __logf(sum)) - scal[0];
    }
}

// ---------------------------------------------------------------------------
extern "C" void kernel_launch(void* const* d_in, const int* in_sizes, int n_in,
                              void* d_out, int out_size, void* d_ws, size_t ws_size,
                              hipStream_t stream) {
    const int*   sentence = (const int*)d_in[0];
    const int*   chars    = (const int*)d_in[1];
    const int*   tags     = (const int*)d_in[2];
    const float* wemb     = (const float*)d_in[4];
    const float* cemb     = (const float*)d_in[5];
    const float* convw    = (const float*)d_in[6];
    const float* convb    = (const float*)d_in[7];
    const float* wihf     = (const float*)d_in[8];
    const float* whhf     = (const float*)d_in[9];
    const float* bf       = (const float*)d_in[10];
    const float* wihb     = (const float*)d_in[11];
    const float* whhb     = (const float*)d_in[12];
    const float* bb       = (const float*)d_in[13];
    const float* wtag     = (const float*)d_in[14];
    const float* btag     = (const float*)d_in[15];
    const float* trans    = (const float*)d_in[16];

    char* ws = (char*)d_ws;
    float*        embeds = (float*)(ws + WS_EMBEDS);
    float*        gi     = (float*)(ws + WS_GI);
    unsigned int* wpk    = (unsigned int*)(ws + WS_WPK);
    unsigned int* xh     = (unsigned int*)(ws + WS_XH);
    int*          flags  = (int*)(ws + WS_FLAGS);
    float*        cfeat  = (float*)(ws + WS_CFEAT);
    float*        hsbuf  = (float*)(ws + WS_HS);
    float*        feats  = (float*)(ws + WS_FEATS);
    float*        chunks = (float*)(ws + WS_CHUNKS);
    float*        lvl2   = (float*)(ws + WS_LVL2);
    float*        scal   = (float*)(ws + WS_SCAL);

    k_pack<<<8, 256, 0, stream>>>(whhf, whhb, wpk);
    k_charcnn<<<4096, 128, 0, stream>>>(chars, cemb, convw, convb, cfeat);
    k_embeds<<<4096, 128, 0, stream>>>(sentence, wemb, cfeat, embeds);
    k_gemm<<<dim3(64, 32), 256, 0, stream>>>(embeds, wihf, wihb, bf, bb, gi);
    k_lstm<<<4, 512, 0, stream>>>(wpk, gi, xh, flags, hsbuf);
    k_feats<<<4096, 192, 0, stream>>>(hsbuf, wtag, btag, feats);
    k_gold<<<1, 256, 0, stream>>>(feats, tags, trans, scal);
    k_crf1<<<256, 192, 0, stream>>>(feats, trans, chunks);
    k_crf2<<<16, 192, 0, stream>>>(chunks, lvl2);
    k_crf3<<<1, 192, 0, stream>>>(lvl2, trans, scal, (float*)d_out);
}